// Round 1
// baseline (283.704 us; speedup 1.0000x reference)
//
#include <hip/hip_runtime.h>

#define D_MODEL 1024
#define NHEADS  16
#define HDIM    64
#define BATCH   2
#define SEQ     2048
#define ROWS    (BATCH*SEQ)      // 4096
#define CHUNK   128
#define NCHUNK  (SEQ/CHUNK)      // 16
#define LN_EPS  1e-3f

typedef unsigned short ushort_t;
typedef __attribute__((ext_vector_type(4))) float          f32x4;
typedef __attribute__((ext_vector_type(8))) short          s16x8;
typedef __attribute__((ext_vector_type(4))) unsigned short u16x4;
typedef __attribute__((ext_vector_type(8))) unsigned short u16x8;

__device__ __forceinline__ ushort_t f2b(float f) {
    union { float f; unsigned int u; } v; v.f = f;
    unsigned int r = v.u + 0x7fffu + ((v.u >> 16) & 1u);
    return (ushort_t)(r >> 16);
}
__device__ __forceinline__ float b2f(ushort_t b) {
    union { unsigned int u; float f; } v; v.u = ((unsigned int)b) << 16;
    return v.f;
}

// ---------------------------------------------------------------- cast x -> bf16
__global__ __launch_bounds__(256) void cast_x_kernel(const float* __restrict__ x,
                                                     ushort_t* __restrict__ xb) {
    int idx = (blockIdx.x * 256 + threadIdx.x) * 4;
    f32x4 v = *(const f32x4*)(x + idx);
    u16x4 o;
    o.x = f2b(v.x); o.y = f2b(v.y); o.z = f2b(v.z); o.w = f2b(v.w);
    *(u16x4*)(xb + idx) = o;
}

// ------------------------------------------- transpose+cast weights: WT[n][k] = W[k][n]
__global__ __launch_bounds__(256) void wt_transpose_kernel(
        const float* __restrict__ Wq, const float* __restrict__ Wk,
        const float* __restrict__ Wv, const float* __restrict__ Wg,
        const float* __restrict__ Wo,
        ushort_t* __restrict__ WcatT, ushort_t* __restrict__ WoT) {
    __shared__ float tile[32][33];
    int z = blockIdx.z;
    const float* W = (z == 0) ? Wq : (z == 1) ? Wk : (z == 2) ? Wv : (z == 3) ? Wg : Wo;
    ushort_t* dst = (z < 4) ? (WcatT + (size_t)z * 1024 * 1024) : WoT;
    int n0 = blockIdx.x * 32, k0 = blockIdx.y * 32;
    int tx = threadIdx.x, ty = threadIdx.y;
#pragma unroll
    for (int i = 0; i < 4; i++) {
        int k = k0 + ty + i * 8;
        tile[ty + i * 8][tx] = W[(size_t)k * 1024 + n0 + tx];
    }
    __syncthreads();
#pragma unroll
    for (int i = 0; i < 4; i++) {
        int n = n0 + ty + i * 8;
        dst[(size_t)n * 1024 + k0 + tx] = f2b(tile[tx][ty + i * 8]);
    }
}

// ---------------------------------------------------------------- bf16 MFMA GEMM
// C[M x N] = A[M x K] @ B[K x N], with B supplied pre-transposed (BT[n][k]).
// mode 0: N=4096 fused QKVG epilogue -> Y bf16 (Q scaled 1/8, G = swish(.+bg))
// mode 1: N=1024, out fp32 = C + bo
#define LDW 72   // 64 + 8 pad: 144B row stride, 16B aligned, 2-way-free banks
__global__ __launch_bounds__(256, 2) void gemm_kernel(
        const ushort_t* __restrict__ A, const ushort_t* __restrict__ BT,
        int K, int N, int mode, const float* __restrict__ bias,
        ushort_t* __restrict__ Yout, float* __restrict__ Fout) {
    extern __shared__ char smem[];
    ushort_t* As = (ushort_t*)smem;          // [128][72]
    ushort_t* Bs = As + 128 * LDW;           // [128][72]
    int t = threadIdx.x;
    int row0 = blockIdx.y * 128, col0 = blockIdx.x * 128;
    int w = t >> 6, lane = t & 63;
    int wr = (w >> 1) * 64, wc = (w & 1) * 64;
    int qd = lane >> 4, ln = lane & 15;

    f32x4 acc[4][4];
#pragma unroll
    for (int i = 0; i < 4; i++)
#pragma unroll
        for (int j = 0; j < 4; j++) acc[i][j] = (f32x4)0.0f;

    for (int k0 = 0; k0 < K; k0 += 64) {
        // stage A tile [128x64] and BT tile [128x64]
#pragma unroll
        for (int g = t; g < 1024; g += 256) {
            int r = g >> 3, kg = (g & 7) << 3;
            *(u16x8*)(As + r * LDW + kg) =
                *(const u16x8*)(A + (size_t)(row0 + r) * K + k0 + kg);
            *(u16x8*)(Bs + r * LDW + kg) =
                *(const u16x8*)(BT + (size_t)(col0 + r) * K + k0 + kg);
        }
        __syncthreads();
#pragma unroll
        for (int kk = 0; kk < 64; kk += 32) {
            s16x8 af[4], bf[4];
#pragma unroll
            for (int i = 0; i < 4; i++)
                af[i] = *(const s16x8*)(As + (wr + i * 16 + ln) * LDW + kk + qd * 8);
#pragma unroll
            for (int j = 0; j < 4; j++)
                bf[j] = *(const s16x8*)(Bs + (wc + j * 16 + ln) * LDW + kk + qd * 8);
#pragma unroll
            for (int i = 0; i < 4; i++)
#pragma unroll
                for (int j = 0; j < 4; j++)
                    acc[i][j] = __builtin_amdgcn_mfma_f32_16x16x32_bf16(
                        af[i], bf[j], acc[i][j], 0, 0, 0);
        }
        __syncthreads();
    }

    // epilogue: lane holds C[row0+wr+i*16+qd*4+r][col0+wc+j*16+ln]
#pragma unroll
    for (int i = 0; i < 4; i++)
#pragma unroll
        for (int j = 0; j < 4; j++) {
            int n = col0 + wc + j * 16 + ln;
#pragma unroll
            for (int r = 0; r < 4; r++) {
                int m = row0 + wr + i * 16 + qd * 4 + r;
                float v = acc[i][j][r];
                if (mode == 0) {
                    int region = n >> 10;
                    if (region == 0) v *= 0.125f;                       // Q / sqrt(dh)
                    else if (region == 3) {                             // G = swish
                        v += bias[n & 1023];
                        v = v / (1.0f + __expf(-v));
                    }
                    Yout[(size_t)m * N + n] = f2b(v);
                } else {
                    Fout[(size_t)m * N + n] = v + bias[n];
                }
            }
        }
}

// ------------------------------------- per-chunk decayed KV state: A_c = K^T diag(g^(127-j)) V
__global__ __launch_bounds__(256) void chunk_states_kernel(const ushort_t* __restrict__ Y,
                                                           float* __restrict__ Astate) {
    __shared__ float Kw[64 * 64];
    __shared__ float Vv[64 * 64];
    int c = blockIdx.x, h = blockIdx.y, b = blockIdx.z;
    int t = threadIdx.x;
    float gamma = 1.0f - exp2f(-5.0f - (float)h);
    float l2g = log2f(gamma);
    int row0 = b * SEQ + c * CHUNK;
    int colK = D_MODEL + h * HDIM;
    int colV = 2 * D_MODEL + h * HDIM;
    int dq = (t & 15) * 4, d1b = t >> 4;

    f32x4 acc[4];
#pragma unroll
    for (int a = 0; a < 4; a++) acc[a] = (f32x4)0.0f;

    for (int half = 0; half < 2; half++) {
        __syncthreads();
        for (int l = t; l < 4096; l += 256) {
            int j = l >> 6, d = l & 63;
            int jj = half * 64 + j;
            size_t row = (size_t)(row0 + jj) * 4096;
            Kw[j * 64 + d] = b2f(Y[row + colK + d]) * exp2f((float)(127 - jj) * l2g);
            Vv[j * 64 + d] = b2f(Y[row + colV + d]);
        }
        __syncthreads();
#pragma unroll 4
        for (int j = 0; j < 64; j++) {
            f32x4 v4 = *(const f32x4*)(Vv + j * 64 + dq);
#pragma unroll
            for (int a = 0; a < 4; a++) {
                float kv = Kw[j * 64 + d1b + 16 * a];
                acc[a] += kv * v4;
            }
        }
    }
    size_t base = ((size_t)((b * NHEADS + h) * NCHUNK + c)) * 4096;
#pragma unroll
    for (int a = 0; a < 4; a++)
        *(f32x4*)(Astate + base + (size_t)(d1b + 16 * a) * 64 + dq) = acc[a];
}

// --------------------------------------------- exclusive decay scan over chunk states
__global__ __launch_bounds__(256) void scan_kernel(const float* __restrict__ Astate,
                                                   float* __restrict__ Sprev) {
    int h = blockIdx.x, b = blockIdx.y;
    int bh = b * NHEADS + h;
    float gamma = 1.0f - exp2f(-5.0f - (float)h);
    float gC = exp2f(128.0f * log2f(gamma));
    for (int g = threadIdx.x; g < 1024; g += 256) {
        f32x4 S = (f32x4)0.0f;
        for (int c = 0; c < NCHUNK; c++) {
            size_t off = ((size_t)bh * NCHUNK + c) * 4096 + g * 4;
            *(f32x4*)(Sprev + off) = S;
            f32x4 Ain = *(const f32x4*)(Astate + off);
            S = S * gC + Ain;
        }
    }
}

// --------------------------------------------- per-chunk retention output
// out[i][d] = g^(i+1) * (Q_i . Sprev[:,d])  +  sum_{j<=i} g^(i-j) (Q_i.K_j) V_j[d]
#define P_LDW 132
__global__ __launch_bounds__(256, 1) void chunk_out_kernel(const ushort_t* __restrict__ Y,
                                                           const float* __restrict__ Sprev,
                                                           float* __restrict__ ret) {
    extern __shared__ char smem[];
    ushort_t* Qs = (ushort_t*)smem;              // [128][72] bf16
    ushort_t* Kc = Qs + 128 * LDW;               // [128][72] bf16
    ushort_t* Vc = Kc + 128 * LDW;               // [128][72] bf16
    float*    Sp = (float*)(Vc + 128 * LDW);     // [64][72]  fp32
    float*    Pl = Sp + 64 * LDW;                // [128][132] fp32
    int c = blockIdx.x, h = blockIdx.y, b = blockIdx.z;
    int t = threadIdx.x;
    float gamma = 1.0f - exp2f(-5.0f - (float)h);
    float l2g = log2f(gamma);
    int row0 = b * SEQ + c * CHUNK;

    // stage Q,K,V (bf16) and Sprev (fp32)
    for (int g = t; g < 1024; g += 256) {
        int i = g >> 3, dg = (g & 7) * 8;
        size_t src = (size_t)(row0 + i) * 4096 + h * HDIM + dg;
        *(u16x8*)(Qs + i * LDW + dg) = *(const u16x8*)(Y + src);
        *(u16x8*)(Kc + i * LDW + dg) = *(const u16x8*)(Y + src + D_MODEL);
        *(u16x8*)(Vc + i * LDW + dg) = *(const u16x8*)(Y + src + 2 * D_MODEL);
    }
    {
        size_t sbase = ((size_t)((b * NHEADS + h) * NCHUNK + c)) * 4096;
        for (int g = t; g < 1024; g += 256) {
            int e = g >> 4, dg = (g & 15) * 4;
            *(f32x4*)(Sp + e * LDW + dg) = *(const f32x4*)(Sprev + sbase + e * 64 + dg);
        }
    }
    __syncthreads();

    int dq = (t & 15) * 4;   // d column quad
    int ic = t >> 4;         // base row
    int jc = t & 15;

    // ---- phase 1: inter-chunk term acc = Q @ Sprev (then row-scaled)
    f32x4 acc[8];
#pragma unroll
    for (int a = 0; a < 8; a++) acc[a] = (f32x4)0.0f;
#pragma unroll 2
    for (int e4 = 0; e4 < 16; e4++) {
        f32x4 sp[4];
#pragma unroll
        for (int r = 0; r < 4; r++)
            sp[r] = *(const f32x4*)(Sp + (e4 * 4 + r) * LDW + dq);
#pragma unroll
        for (int a = 0; a < 8; a++) {
            u16x4 uq = *(const u16x4*)(Qs + (ic + 16 * a) * LDW + e4 * 4);
            acc[a] += b2f(uq.x) * sp[0] + b2f(uq.y) * sp[1] +
                      b2f(uq.z) * sp[2] + b2f(uq.w) * sp[3];
        }
    }
#pragma unroll
    for (int a = 0; a < 8; a++)
        acc[a] *= exp2f((float)(ic + 16 * a + 1) * l2g);

    // ---- phase 2: P = tril(Q K^T) * decay  -> LDS
    for (int half = 0; half < 2; half++) {
        float dotP[8][4];
#pragma unroll
        for (int a = 0; a < 8; a++)
#pragma unroll
            for (int bb = 0; bb < 4; bb++) dotP[a][bb] = 0.0f;
#pragma unroll 2
        for (int e4 = 0; e4 < 16; e4++) {
            float qv[8][4];
#pragma unroll
            for (int a = 0; a < 8; a++) {
                u16x4 uq = *(const u16x4*)(Qs + (ic + 16 * a) * LDW + e4 * 4);
                qv[a][0] = b2f(uq.x); qv[a][1] = b2f(uq.y);
                qv[a][2] = b2f(uq.z); qv[a][3] = b2f(uq.w);
            }
#pragma unroll
            for (int bb = 0; bb < 4; bb++) {
                int j = jc + 16 * (half * 4 + bb);
                u16x4 uk = *(const u16x4*)(Kc + j * LDW + e4 * 4);
                float k0 = b2f(uk.x), k1 = b2f(uk.y), k2 = b2f(uk.z), k3 = b2f(uk.w);
#pragma unroll
                for (int a = 0; a < 8; a++)
                    dotP[a][bb] += qv[a][0] * k0 + qv[a][1] * k1 +
                                   qv[a][2] * k2 + qv[a][3] * k3;
            }
        }
#pragma unroll
        for (int a = 0; a < 8; a++) {
            int i = ic + 16 * a;
#pragma unroll
            for (int bb = 0; bb < 4; bb++) {
                int j = jc + 16 * (half * 4 + bb);
                float v = (j <= i) ? dotP[a][bb] * exp2f((float)(i - j) * l2g) : 0.0f;
                Pl[i * P_LDW + j] = v;
            }
        }
    }
    __syncthreads();

    // ---- phase 3: acc += P @ V
#pragma unroll 2
    for (int j4 = 0; j4 < 32; j4++) {
        f32x4 vv[4];
#pragma unroll
        for (int r = 0; r < 4; r++) {
            u16x4 uv = *(const u16x4*)(Vc + (j4 * 4 + r) * LDW + dq);
            vv[r].x = b2f(uv.x); vv[r].y = b2f(uv.y);
            vv[r].z = b2f(uv.z); vv[r].w = b2f(uv.w);
        }
#pragma unroll
        for (int a = 0; a < 8; a++) {
            f32x4 p4 = *(const f32x4*)(Pl + (ic + 16 * a) * P_LDW + j4 * 4);
            acc[a] += p4.x * vv[0] + p4.y * vv[1] + p4.z * vv[2] + p4.w * vv[3];
        }
    }

#pragma unroll
    for (int a = 0; a < 8; a++) {
        int i = ic + 16 * a;
        *(f32x4*)(ret + (size_t)(row0 + i) * D_MODEL + h * HDIM + dq) = acc[a];
    }
}

// ---------------------------------------------------------------- LayerNorm * gate
__global__ __launch_bounds__(256) void ln_gate_kernel(const float* __restrict__ ret,
                                                      const ushort_t* __restrict__ Y,
                                                      const float* __restrict__ lgam,
                                                      const float* __restrict__ lbet,
                                                      ushort_t* __restrict__ LNG) {
    int row = blockIdx.x, t = threadIdx.x;
    f32x4 v = *(const f32x4*)(ret + (size_t)row * D_MODEL + t * 4);
    float s  = v.x + v.y + v.z + v.w;
    float sq = v.x * v.x + v.y * v.y + v.z * v.z + v.w * v.w;
#pragma unroll
    for (int m = 1; m < 64; m <<= 1) {
        s  += __shfl_xor(s, m);
        sq += __shfl_xor(sq, m);
    }
    __shared__ float red[8];
    int w = t >> 6, lane = t & 63;
    if (lane == 0) { red[w * 2] = s; red[w * 2 + 1] = sq; }
    __syncthreads();
    s  = red[0] + red[2] + red[4] + red[6];
    sq = red[1] + red[3] + red[5] + red[7];
    float mu  = s * (1.0f / 1024.0f);
    float var = sq * (1.0f / 1024.0f) - mu * mu;
    float inv = rsqrtf(var + LN_EPS);
    int col = t * 4;
    u16x4 ug = *(const u16x4*)(Y + (size_t)row * 4096 + 3 * D_MODEL + col);
    u16x4 o;
    o.x = f2b(((v.x - mu) * inv * lgam[col + 0] + lbet[col + 0]) * b2f(ug.x));
    o.y = f2b(((v.y - mu) * inv * lgam[col + 1] + lbet[col + 1]) * b2f(ug.y));
    o.z = f2b(((v.z - mu) * inv * lgam[col + 2] + lbet[col + 2]) * b2f(ug.z));
    o.w = f2b(((v.w - mu) * inv * lgam[col + 3] + lbet[col + 3]) * b2f(ug.w));
    *(u16x4*)(LNG + (size_t)row * D_MODEL + col) = o;
}

// ----------------------------------------------------------------------------
extern "C" void kernel_launch(void* const* d_in, const int* in_sizes, int n_in,
                              void* d_out, int out_size, void* d_ws, size_t ws_size,
                              hipStream_t stream) {
    const float* x   = (const float*)d_in[0];
    const float* Wq  = (const float*)d_in[1];
    const float* Wk  = (const float*)d_in[2];
    const float* Wv  = (const float*)d_in[3];
    const float* Wg  = (const float*)d_in[4];
    const float* bg  = (const float*)d_in[5];
    const float* Wo  = (const float*)d_in[6];
    const float* bo  = (const float*)d_in[7];
    const float* lng = (const float*)d_in[8];
    const float* lnb = (const float*)d_in[9];
    float* out = (float*)d_out;

    char* ws = (char*)d_ws;
    ushort_t* xb    = (ushort_t*)(ws);                       //  8 MB  x bf16
    ushort_t* WcatT = (ushort_t*)(ws + (8ull  << 20));       //  8 MB  [Wq|Wk|Wv|Wg]^T bf16
    ushort_t* WoT   = (ushort_t*)(ws + (16ull << 20));       //  2 MB  Wo^T bf16
    ushort_t* Yb    = (ushort_t*)(ws + (18ull << 20));       // 32 MB  [Q/8|K|V|G] bf16
    float*    retb  = (float*)   (ws + (50ull << 20));       // 16 MB  retention out fp32
    float*    Ast   = (float*)   (ws + (66ull << 20));       //  8 MB  chunk states
    float*    Sprv  = (float*)   (ws + (74ull << 20));       //  8 MB  exclusive-scan states
    ushort_t* LNGb  = (ushort_t*)(ws + (82ull << 20));       //  8 MB  (ln*G) bf16   -> 90 MB total

    hipFuncSetAttribute(reinterpret_cast<const void*>(gemm_kernel),
                        hipFuncAttributeMaxDynamicSharedMemorySize, 2 * 128 * LDW * 2);
    hipFuncSetAttribute(reinterpret_cast<const void*>(chunk_out_kernel),
                        hipFuncAttributeMaxDynamicSharedMemorySize,
                        3 * 128 * LDW * 2 + 64 * LDW * 4 + 128 * P_LDW * 4);

    cast_x_kernel<<<ROWS * D_MODEL / 1024, 256, 0, stream>>>(x, xb);
    wt_transpose_kernel<<<dim3(32, 32, 5), dim3(32, 8), 0, stream>>>(
        Wq, Wk, Wv, Wg, Wo, WcatT, WoT);

    gemm_kernel<<<dim3(32, 32), 256, 2 * 128 * LDW * 2, stream>>>(
        xb, WcatT, 1024, 4096, 0, bg, Yb, (float*)nullptr);

    chunk_states_kernel<<<dim3(NCHUNK, NHEADS, BATCH), 256, 0, stream>>>(Yb, Ast);
    scan_kernel<<<dim3(NHEADS, BATCH), 256, 0, stream>>>(Ast, Sprv);
    chunk_out_kernel<<<dim3(NCHUNK, NHEADS, BATCH), 256,
                       3 * 128 * LDW * 2 + 64 * LDW * 4 + 128 * P_LDW * 4, stream>>>(
        Yb, Sprv, retb);

    ln_gate_kernel<<<ROWS, 256, 0, stream>>>(retb, Yb, lng, lnb, LNGb);

    gemm_kernel<<<dim3(8, 32), 256, 2 * 128 * LDW * 2, stream>>>(
        LNGb, WoT, 1024, 1024, 1, bo, (ushort_t*)nullptr, out);
}

// Round 2
// 235.933 us; speedup vs baseline: 1.2025x; 1.2025x over previous
//
#include <hip/hip_runtime.h>

#define D_MODEL 1024
#define NHEADS  16
#define HDIM    64
#define BATCH   2
#define SEQ     2048
#define ROWS    (BATCH*SEQ)      // 4096
#define CHUNK   128
#define NCHUNK  (SEQ/CHUNK)      // 16
#define LN_EPS  1e-3f

typedef unsigned short ushort_t;
typedef __attribute__((ext_vector_type(4))) float          f32x4;
typedef __attribute__((ext_vector_type(8))) short          s16x8;
typedef __attribute__((ext_vector_type(4))) unsigned short u16x4;
typedef __attribute__((ext_vector_type(8))) unsigned short u16x8;

__device__ __forceinline__ ushort_t f2b(float f) {
    union { float f; unsigned int u; } v; v.f = f;
    unsigned int r = v.u + 0x7fffu + ((v.u >> 16) & 1u);
    return (ushort_t)(r >> 16);
}
__device__ __forceinline__ float b2f(ushort_t b) {
    union { unsigned int u; float f; } v; v.u = ((unsigned int)b) << 16;
    return v.f;
}

// ---------------------------------------------------------------- cast x -> bf16
__global__ __launch_bounds__(256) void cast_x_kernel(const float* __restrict__ x,
                                                     ushort_t* __restrict__ xb) {
    int idx = (blockIdx.x * 256 + threadIdx.x) * 4;
    f32x4 v = *(const f32x4*)(x + idx);
    u16x4 o;
    o.x = f2b(v.x); o.y = f2b(v.y); o.z = f2b(v.z); o.w = f2b(v.w);
    *(u16x4*)(xb + idx) = o;
}

// ------------------------------------------- transpose+cast weights: WT[n][k] = W[k][n]
__global__ __launch_bounds__(256) void wt_transpose_kernel(
        const float* __restrict__ Wq, const float* __restrict__ Wk,
        const float* __restrict__ Wv, const float* __restrict__ Wg,
        const float* __restrict__ Wo,
        ushort_t* __restrict__ WcatT, ushort_t* __restrict__ WoT) {
    __shared__ float tile[32][33];
    int z = blockIdx.z;
    const float* W = (z == 0) ? Wq : (z == 1) ? Wk : (z == 2) ? Wv : (z == 3) ? Wg : Wo;
    ushort_t* dst = (z < 4) ? (WcatT + (size_t)z * 1024 * 1024) : WoT;
    int n0 = blockIdx.x * 32, k0 = blockIdx.y * 32;
    int tx = threadIdx.x, ty = threadIdx.y;
#pragma unroll
    for (int i = 0; i < 4; i++) {
        int k = k0 + ty + i * 8;
        tile[ty + i * 8][tx] = W[(size_t)k * 1024 + n0 + tx];
    }
    __syncthreads();
#pragma unroll
    for (int i = 0; i < 4; i++) {
        int n = n0 + ty + i * 8;
        dst[(size_t)n * 1024 + k0 + tx] = f2b(tile[tx][ty + i * 8]);
    }
}

// ---------------------------------------------------------------- bf16 MFMA GEMM
// C[M x N] = A[M x K] @ B[K x N], with B supplied pre-transposed (BT[n][k]).
// mode 0: N=4096 fused QKVG epilogue -> Y bf16 (Q scaled 1/8, G = swish(.+bg))
// mode 1: N=1024, out fp32 = C + bo
#define LDW 72   // 64 + 8 pad
__global__ __launch_bounds__(256, 2) void gemm_kernel(
        const ushort_t* __restrict__ A, const ushort_t* __restrict__ BT,
        int K, int N, int mode, const float* __restrict__ bias,
        ushort_t* __restrict__ Yout, float* __restrict__ Fout) {
    extern __shared__ char smem[];
    ushort_t* As = (ushort_t*)smem;          // [128][72]
    ushort_t* Bs = As + 128 * LDW;           // [128][72]
    int t = threadIdx.x;
    int row0 = blockIdx.y * 128, col0 = blockIdx.x * 128;
    int w = t >> 6, lane = t & 63;
    int wr = (w >> 1) * 64, wc = (w & 1) * 64;
    int qd = lane >> 4, ln = lane & 15;

    f32x4 acc[4][4];
#pragma unroll
    for (int i = 0; i < 4; i++)
#pragma unroll
        for (int j = 0; j < 4; j++) acc[i][j] = (f32x4)0.0f;

    for (int k0 = 0; k0 < K; k0 += 64) {
#pragma unroll
        for (int g = t; g < 1024; g += 256) {
            int r = g >> 3, kg = (g & 7) << 3;
            *(u16x8*)(As + r * LDW + kg) =
                *(const u16x8*)(A + (size_t)(row0 + r) * K + k0 + kg);
            *(u16x8*)(Bs + r * LDW + kg) =
                *(const u16x8*)(BT + (size_t)(col0 + r) * K + k0 + kg);
        }
        __syncthreads();
#pragma unroll
        for (int kk = 0; kk < 64; kk += 32) {
            s16x8 af[4], bf[4];
#pragma unroll
            for (int i = 0; i < 4; i++)
                af[i] = *(const s16x8*)(As + (wr + i * 16 + ln) * LDW + kk + qd * 8);
#pragma unroll
            for (int j = 0; j < 4; j++)
                bf[j] = *(const s16x8*)(Bs + (wc + j * 16 + ln) * LDW + kk + qd * 8);
#pragma unroll
            for (int i = 0; i < 4; i++)
#pragma unroll
                for (int j = 0; j < 4; j++)
                    acc[i][j] = __builtin_amdgcn_mfma_f32_16x16x32_bf16(
                        af[i], bf[j], acc[i][j], 0, 0, 0);
        }
        __syncthreads();
    }

#pragma unroll
    for (int i = 0; i < 4; i++)
#pragma unroll
        for (int j = 0; j < 4; j++) {
            int n = col0 + wc + j * 16 + ln;
#pragma unroll
            for (int r = 0; r < 4; r++) {
                int m = row0 + wr + i * 16 + qd * 4 + r;
                float v = acc[i][j][r];
                if (mode == 0) {
                    int region = n >> 10;
                    if (region == 0) v *= 0.125f;                       // Q / sqrt(dh)
                    else if (region == 3) {                             // G = swish
                        v += bias[n & 1023];
                        v = v / (1.0f + __expf(-v));
                    }
                    Yout[(size_t)m * N + n] = f2b(v);
                } else {
                    Fout[(size_t)m * N + n] = v + bias[n];
                }
            }
        }
}

// ------------------------------------- per-chunk decayed KV state: A_c = K^T diag(g^(127-j)) V
__global__ __launch_bounds__(256) void chunk_states_kernel(const ushort_t* __restrict__ Y,
                                                           float* __restrict__ Astate) {
    __shared__ float Kw[64 * 64];
    __shared__ float Vv[64 * 64];
    int c = blockIdx.x, h = blockIdx.y, b = blockIdx.z;
    int t = threadIdx.x;
    float gamma = 1.0f - exp2f(-5.0f - (float)h);
    float l2g = log2f(gamma);
    int row0 = b * SEQ + c * CHUNK;
    int colK = D_MODEL + h * HDIM;
    int colV = 2 * D_MODEL + h * HDIM;
    int dq = (t & 15) * 4, d1b = t >> 4;

    f32x4 acc[4];
#pragma unroll
    for (int a = 0; a < 4; a++) acc[a] = (f32x4)0.0f;

    for (int half = 0; half < 2; half++) {
        __syncthreads();
        for (int l = t; l < 4096; l += 256) {
            int j = l >> 6, d = l & 63;
            int jj = half * 64 + j;
            size_t row = (size_t)(row0 + jj) * 4096;
            Kw[j * 64 + d] = b2f(Y[row + colK + d]) * exp2f((float)(127 - jj) * l2g);
            Vv[j * 64 + d] = b2f(Y[row + colV + d]);
        }
        __syncthreads();
#pragma unroll 4
        for (int j = 0; j < 64; j++) {
            f32x4 v4 = *(const f32x4*)(Vv + j * 64 + dq);
#pragma unroll
            for (int a = 0; a < 4; a++) {
                float kv = Kw[j * 64 + d1b + 16 * a];
                acc[a] += kv * v4;
            }
        }
    }
    size_t base = ((size_t)((b * NHEADS + h) * NCHUNK + c)) * 4096;
#pragma unroll
    for (int a = 0; a < 4; a++)
        *(f32x4*)(Astate + base + (size_t)(d1b + 16 * a) * 64 + dq) = acc[a];
}

// --------------------------------------------- exclusive decay scan over chunk states
__global__ __launch_bounds__(256) void scan_kernel(const float* __restrict__ Astate,
                                                   float* __restrict__ Sprev) {
    int h = blockIdx.x, b = blockIdx.y;
    int bh = b * NHEADS + h;
    float gamma = 1.0f - exp2f(-5.0f - (float)h);
    float gC = exp2f(128.0f * log2f(gamma));
    for (int g = threadIdx.x; g < 1024; g += 256) {
        f32x4 S = (f32x4)0.0f;
        for (int c = 0; c < NCHUNK; c++) {
            size_t off = ((size_t)bh * NCHUNK + c) * 4096 + g * 4;
            *(f32x4*)(Sprev + off) = S;
            f32x4 Ain = *(const f32x4*)(Astate + off);
            S = S * gC + Ain;
        }
    }
}

// --------------------------------------------- per-chunk retention output (MFMA)
// out[i][d] = g^(i+1)*(Q_i . Sprev[:,d]) + sum_{j<=i} g^(i-j) (Q_i.K_j) V_j[d]
// LDS (elements, bf16): Qs[128][72] | Kc[128][72] | Sphi[64][72] | Splo[64][72] | Vt[64][136]
// P[128][136] overlays Qs+Kc after phase 2.
#define VT_LDW 136
#define CO_ELEMS (128*LDW*2 + 64*LDW*2 + 64*VT_LDW)   // 36352 elems = 72704 B
__global__ __launch_bounds__(256, 2) void chunk_out_kernel(const ushort_t* __restrict__ Y,
                                                           const float* __restrict__ Sprev,
                                                           float* __restrict__ ret) {
    extern __shared__ char smem[];
    ushort_t* Qs   = (ushort_t*)smem;            // [128][72]
    ushort_t* Kc   = Qs + 128 * LDW;             // [128][72]
    ushort_t* Sphi = Kc + 128 * LDW;             // [64][72]
    ushort_t* Splo = Sphi + 64 * LDW;            // [64][72]
    ushort_t* Vt   = Splo + 64 * LDW;            // [64][136]  V^T[d][j]
    ushort_t* Pl   = Qs;                         // [128][136] overlays Qs+Kc (34816B <= 36864B)

    int c = blockIdx.x, h = blockIdx.y, b = blockIdx.z;
    int t = threadIdx.x;
    float gamma = 1.0f - exp2f(-5.0f - (float)h);
    float l2g = log2f(gamma);
    int row0 = b * SEQ + c * CHUNK;

    // ---- stage Q,K (row-major) and V transposed
    for (int g = t; g < 1024; g += 256) {
        int i = g >> 3, dg = (g & 7) * 8;
        size_t src = (size_t)(row0 + i) * 4096 + h * HDIM + dg;
        *(u16x8*)(Qs + i * LDW + dg) = *(const u16x8*)(Y + src);
        *(u16x8*)(Kc + i * LDW + dg) = *(const u16x8*)(Y + src + D_MODEL);
        u16x8 v = *(const u16x8*)(Y + src + 2 * D_MODEL);
#pragma unroll
        for (int k2 = 0; k2 < 8; k2++) Vt[(dg + k2) * VT_LDW + i] = v[k2];
    }
    // ---- stage Sprev transposed, hi/lo bf16 split
    {
        size_t sbase = ((size_t)((b * NHEADS + h) * NCHUNK + c)) * 4096;
        for (int g = t; g < 1024; g += 256) {
            int e = g >> 4, dg = (g & 15) * 4;
            f32x4 s4 = *(const f32x4*)(Sprev + sbase + e * 64 + dg);
#pragma unroll
            for (int k2 = 0; k2 < 4; k2++) {
                float s = s4[k2];
                ushort_t hb = f2b(s);
                float lo = s - b2f(hb);
                Sphi[(dg + k2) * LDW + e] = hb;
                Splo[(dg + k2) * LDW + e] = f2b(lo);
            }
        }
    }
    __syncthreads();

    int w = t >> 6, lane = t & 63;
    int wr = w * 32;             // this wave's 32 output rows
    int qd = lane >> 4, ln = lane & 15;

    // A fragments of Q (shared by phases 1 & 2)
    s16x8 aq[2][2];
#pragma unroll
    for (int mt = 0; mt < 2; mt++)
#pragma unroll
        for (int ks = 0; ks < 2; ks++)
            aq[mt][ks] = *(const s16x8*)(Qs + (wr + mt * 16 + ln) * LDW + ks * 32 + qd * 8);

    // decay tables (per lane)
    float prow[2][4], pcolm[8];
#pragma unroll
    for (int mt = 0; mt < 2; mt++)
#pragma unroll
        for (int r = 0; r < 4; r++)
            prow[mt][r] = exp2f((float)(wr + mt * 16 + qd * 4 + r + 1) * l2g);  // g^(i+1)
#pragma unroll
    for (int nt = 0; nt < 8; nt++)
        pcolm[nt] = exp2f(-(float)(nt * 16 + ln + 1) * l2g);                    // g^-(j+1)

    // ---- phase 1: out = Q @ Sprev (hi + lo), then scale by g^(i+1)
    f32x4 out[2][4];
#pragma unroll
    for (int mt = 0; mt < 2; mt++)
#pragma unroll
        for (int dt = 0; dt < 4; dt++) out[mt][dt] = (f32x4)0.0f;
#pragma unroll
    for (int dt = 0; dt < 4; dt++)
#pragma unroll
        for (int ks = 0; ks < 2; ks++) {
            s16x8 bh_ = *(const s16x8*)(Sphi + (dt * 16 + ln) * LDW + ks * 32 + qd * 8);
            s16x8 bl_ = *(const s16x8*)(Splo + (dt * 16 + ln) * LDW + ks * 32 + qd * 8);
#pragma unroll
            for (int mt = 0; mt < 2; mt++) {
                out[mt][dt] = __builtin_amdgcn_mfma_f32_16x16x32_bf16(
                    aq[mt][ks], bh_, out[mt][dt], 0, 0, 0);
                out[mt][dt] = __builtin_amdgcn_mfma_f32_16x16x32_bf16(
                    aq[mt][ks], bl_, out[mt][dt], 0, 0, 0);
            }
        }
#pragma unroll
    for (int mt = 0; mt < 2; mt++)
#pragma unroll
        for (int dt = 0; dt < 4; dt++)
#pragma unroll
            for (int r = 0; r < 4; r++) out[mt][dt][r] *= prow[mt][r];

    // ---- phase 2: scores = Q @ K^T
    f32x4 sc[2][8];
#pragma unroll
    for (int mt = 0; mt < 2; mt++)
#pragma unroll
        for (int nt = 0; nt < 8; nt++) sc[mt][nt] = (f32x4)0.0f;
#pragma unroll
    for (int nt = 0; nt < 8; nt++)
#pragma unroll
        for (int ks = 0; ks < 2; ks++) {
            s16x8 bk = *(const s16x8*)(Kc + (nt * 16 + ln) * LDW + ks * 32 + qd * 8);
#pragma unroll
            for (int mt = 0; mt < 2; mt++)
                sc[mt][nt] = __builtin_amdgcn_mfma_f32_16x16x32_bf16(
                    aq[mt][ks], bk, sc[mt][nt], 0, 0, 0);
        }
    __syncthreads();   // all Qs/Kc/Sp reads done; safe to overlay P

    // ---- decay-mask scores, write P (bf16) to LDS in A-operand layout
#pragma unroll
    for (int mt = 0; mt < 2; mt++)
#pragma unroll
        for (int nt = 0; nt < 8; nt++) {
            int j = nt * 16 + ln;
#pragma unroll
            for (int r = 0; r < 4; r++) {
                int i = wr + mt * 16 + qd * 4 + r;
                float v = (j <= i) ? sc[mt][nt][r] * (prow[mt][r] * pcolm[nt]) : 0.0f;
                Pl[i * VT_LDW + j] = f2b(v);
            }
        }
    __syncthreads();

    // ---- phase 3: out += P @ V
#pragma unroll
    for (int ks = 0; ks < 4; ks++) {
        s16x8 ap[2];
#pragma unroll
        for (int mt = 0; mt < 2; mt++)
            ap[mt] = *(const s16x8*)(Pl + (wr + mt * 16 + ln) * VT_LDW + ks * 32 + qd * 8);
#pragma unroll
        for (int dt = 0; dt < 4; dt++) {
            s16x8 bv = *(const s16x8*)(Vt + (dt * 16 + ln) * VT_LDW + ks * 32 + qd * 8);
#pragma unroll
            for (int mt = 0; mt < 2; mt++)
                out[mt][dt] = __builtin_amdgcn_mfma_f32_16x16x32_bf16(
                    ap[mt], bv, out[mt][dt], 0, 0, 0);
        }
    }

    // ---- store
#pragma unroll
    for (int mt = 0; mt < 2; mt++)
#pragma unroll
        for (int dt = 0; dt < 4; dt++)
#pragma unroll
            for (int r = 0; r < 4; r++) {
                int i = wr + mt * 16 + qd * 4 + r;
                ret[(size_t)(row0 + i) * D_MODEL + h * HDIM + dt * 16 + ln] = out[mt][dt][r];
            }
}

// ---------------------------------------------------------------- LayerNorm * gate
__global__ __launch_bounds__(256) void ln_gate_kernel(const float* __restrict__ ret,
                                                      const ushort_t* __restrict__ Y,
                                                      const float* __restrict__ lgam,
                                                      const float* __restrict__ lbet,
                                                      ushort_t* __restrict__ LNG) {
    int row = blockIdx.x, t = threadIdx.x;
    f32x4 v = *(const f32x4*)(ret + (size_t)row * D_MODEL + t * 4);
    float s  = v.x + v.y + v.z + v.w;
    float sq = v.x * v.x + v.y * v.y + v.z * v.z + v.w * v.w;
#pragma unroll
    for (int m = 1; m < 64; m <<= 1) {
        s  += __shfl_xor(s, m);
        sq += __shfl_xor(sq, m);
    }
    __shared__ float red[8];
    int w = t >> 6, lane = t & 63;
    if (lane == 0) { red[w * 2] = s; red[w * 2 + 1] = sq; }
    __syncthreads();
    s  = red[0] + red[2] + red[4] + red[6];
    sq = red[1] + red[3] + red[5] + red[7];
    float mu  = s * (1.0f / 1024.0f);
    float var = sq * (1.0f / 1024.0f) - mu * mu;
    float inv = rsqrtf(var + LN_EPS);
    int col = t * 4;
    u16x4 ug = *(const u16x4*)(Y + (size_t)row * 4096 + 3 * D_MODEL + col);
    u16x4 o;
    o.x = f2b(((v.x - mu) * inv * lgam[col + 0] + lbet[col + 0]) * b2f(ug.x));
    o.y = f2b(((v.y - mu) * inv * lgam[col + 1] + lbet[col + 1]) * b2f(ug.y));
    o.z = f2b(((v.z - mu) * inv * lgam[col + 2] + lbet[col + 2]) * b2f(ug.z));
    o.w = f2b(((v.w - mu) * inv * lgam[col + 3] + lbet[col + 3]) * b2f(ug.w));
    *(u16x4*)(LNG + (size_t)row * D_MODEL + col) = o;
}

// ----------------------------------------------------------------------------
extern "C" void kernel_launch(void* const* d_in, const int* in_sizes, int n_in,
                              void* d_out, int out_size, void* d_ws, size_t ws_size,
                              hipStream_t stream) {
    const float* x   = (const float*)d_in[0];
    const float* Wq  = (const float*)d_in[1];
    const float* Wk  = (const float*)d_in[2];
    const float* Wv  = (const float*)d_in[3];
    const float* Wg  = (const float*)d_in[4];
    const float* bg  = (const float*)d_in[5];
    const float* Wo  = (const float*)d_in[6];
    const float* bo  = (const float*)d_in[7];
    const float* lng = (const float*)d_in[8];
    const float* lnb = (const float*)d_in[9];
    float* out = (float*)d_out;

    char* ws = (char*)d_ws;
    ushort_t* xb    = (ushort_t*)(ws);                       //  8 MB  x bf16
    ushort_t* WcatT = (ushort_t*)(ws + (8ull  << 20));       //  8 MB  [Wq|Wk|Wv|Wg]^T bf16
    ushort_t* WoT   = (ushort_t*)(ws + (16ull << 20));       //  2 MB  Wo^T bf16
    ushort_t* Yb    = (ushort_t*)(ws + (18ull << 20));       // 32 MB  [Q/8|K|V|G] bf16
    float*    retb  = (float*)   (ws + (50ull << 20));       // 16 MB  retention out fp32
    float*    Ast   = (float*)   (ws + (66ull << 20));       //  8 MB  chunk states
    float*    Sprv  = (float*)   (ws + (74ull << 20));       //  8 MB  exclusive-scan states
    ushort_t* LNGb  = (ushort_t*)(ws + (82ull << 20));       //  8 MB  (ln*G) bf16

    const int CO_BYTES = CO_ELEMS * 2;   // 72704 B dynamic LDS

    hipFuncSetAttribute(reinterpret_cast<const void*>(gemm_kernel),
                        hipFuncAttributeMaxDynamicSharedMemorySize, 2 * 128 * LDW * 2);
    hipFuncSetAttribute(reinterpret_cast<const void*>(chunk_out_kernel),
                        hipFuncAttributeMaxDynamicSharedMemorySize, CO_BYTES);

    cast_x_kernel<<<ROWS * D_MODEL / 1024, 256, 0, stream>>>(x, xb);
    wt_transpose_kernel<<<dim3(32, 32, 5), dim3(32, 8), 0, stream>>>(
        Wq, Wk, Wv, Wg, Wo, WcatT, WoT);

    gemm_kernel<<<dim3(32, 32), 256, 2 * 128 * LDW * 2, stream>>>(
        xb, WcatT, 1024, 4096, 0, bg, Yb, (float*)nullptr);

    chunk_states_kernel<<<dim3(NCHUNK, NHEADS, BATCH), 256, 0, stream>>>(Yb, Ast);
    scan_kernel<<<dim3(NHEADS, BATCH), 256, 0, stream>>>(Ast, Sprv);
    chunk_out_kernel<<<dim3(NCHUNK, NHEADS, BATCH), 256, CO_BYTES, stream>>>(
        Yb, Sprv, retb);

    ln_gate_kernel<<<ROWS, 256, 0, stream>>>(retb, Yb, lng, lnb, LNGb);

    gemm_kernel<<<dim3(8, 32), 256, 2 * 128 * LDW * 2, stream>>>(
        LNGb, WoT, 1024, 1024, 1, bo, (ushort_t*)nullptr, out);
}

// Round 3
// 204.859 us; speedup vs baseline: 1.3849x; 1.1517x over previous
//
#include <hip/hip_runtime.h>

#define D_MODEL 1024
#define NHEADS  16
#define HDIM    64
#define BATCH   2
#define SEQ     2048
#define ROWS    (BATCH*SEQ)      // 4096
#define CHUNK   128
#define NCHUNK  (SEQ/CHUNK)      // 16
#define LN_EPS  1e-3f

typedef unsigned short ushort_t;
typedef __attribute__((ext_vector_type(4))) float          f32x4;
typedef __attribute__((ext_vector_type(8))) short          s16x8;
typedef __attribute__((ext_vector_type(4))) unsigned short u16x4;
typedef __attribute__((ext_vector_type(8))) unsigned short u16x8;

__device__ __forceinline__ ushort_t f2b(float f) {
    union { float f; unsigned int u; } v; v.f = f;
    unsigned int r = v.u + 0x7fffu + ((v.u >> 16) & 1u);
    return (ushort_t)(r >> 16);
}
__device__ __forceinline__ float b2f(ushort_t b) {
    union { unsigned int u; float f; } v; v.u = ((unsigned int)b) << 16;
    return v.f;
}

// async 16B global -> LDS (wave-uniform base + lane*16; m97 pattern)
__device__ __forceinline__ void async_load16(const ushort_t* g, ushort_t* l) {
    __builtin_amdgcn_global_load_lds(
        (const __attribute__((address_space(1))) unsigned int*)(g),
        (__attribute__((address_space(3))) unsigned int*)(l),
        16, 0, 0);
}

// ---------------------------------------------------------------- cast x -> bf16
__global__ __launch_bounds__(256) void cast_x_kernel(const float* __restrict__ x,
                                                     ushort_t* __restrict__ xb) {
    int idx = (blockIdx.x * 256 + threadIdx.x) * 4;
    f32x4 v = *(const f32x4*)(x + idx);
    u16x4 o;
    o.x = f2b(v.x); o.y = f2b(v.y); o.z = f2b(v.z); o.w = f2b(v.w);
    *(u16x4*)(xb + idx) = o;
}

// ------------------------------------------- transpose+cast weights: WT[n][k] = W[k][n]
__global__ __launch_bounds__(256) void wt_transpose_kernel(
        const float* __restrict__ Wq, const float* __restrict__ Wk,
        const float* __restrict__ Wv, const float* __restrict__ Wg,
        const float* __restrict__ Wo,
        ushort_t* __restrict__ WcatT, ushort_t* __restrict__ WoT) {
    __shared__ float tile[32][33];
    int z = blockIdx.z;
    const float* W = (z == 0) ? Wq : (z == 1) ? Wk : (z == 2) ? Wv : (z == 3) ? Wg : Wo;
    ushort_t* dst = (z < 4) ? (WcatT + (size_t)z * 1024 * 1024) : WoT;
    int n0 = blockIdx.x * 32, k0 = blockIdx.y * 32;
    int tx = threadIdx.x, ty = threadIdx.y;
#pragma unroll
    for (int i = 0; i < 4; i++) {
        int k = k0 + ty + i * 8;
        tile[ty + i * 8][tx] = W[(size_t)k * 1024 + n0 + tx];
    }
    __syncthreads();
#pragma unroll
    for (int i = 0; i < 4; i++) {
        int n = n0 + ty + i * 8;
        dst[(size_t)n * 1024 + k0 + tx] = f2b(tile[tx][ty + i * 8]);
    }
}

// ---------------------------------------------------------------- bf16 MFMA GEMM
// C[M x N] = A[M x K] @ B[K x N], B pre-transposed (BT[n][k]).
// m97-style: global_load_lds width=16 staging, unpadded LDS tiles with
// XOR-swizzled 16B blocks (swizzle applied on the GLOBAL source column so the
// LDS destination stays lane-contiguous; fragment reads un-swizzle).
// mode 0: N=4096 fused QKVG epilogue -> Y bf16 (Q scaled 1/8, G = swish(.+bg))
// mode 1: N=1024, out fp32 = C + bo
__global__ __launch_bounds__(256, 2) void gemm_kernel(
        const ushort_t* __restrict__ A, const ushort_t* __restrict__ BT,
        int K, int N, int mode, const float* __restrict__ bias,
        ushort_t* __restrict__ Yout, float* __restrict__ Fout) {
    extern __shared__ char smem[];
    ushort_t* As = (ushort_t*)smem;          // [128][64] swizzled
    ushort_t* Bs = As + 128 * 64;            // [128][64] swizzled
    int t = threadIdx.x;
    int row0 = blockIdx.y * 128, col0 = blockIdx.x * 128;
    int w = t >> 6, lane = t & 63;
    int wr = (w >> 1) * 64, wc = (w & 1) * 64;
    int qd = lane >> 4, ln = lane & 15;
    int lx = ln & 7;                          // XOR key for this lane's rows

    f32x4 acc[4][4];
#pragma unroll
    for (int i = 0; i < 4; i++)
#pragma unroll
        for (int j = 0; j < 4; j++) acc[i][j] = (f32x4)0.0f;

    // per-thread staging source precompute: thread handles items g = p*256+t
    for (int k0 = 0; k0 < K; k0 += 64) {
#pragma unroll
        for (int p = 0; p < 4; p++) {
            int g = p * 256 + t;
            int r = g >> 3;                 // tile row 0..127
            int kb = g & 7;                 // 16B block within row (LDS slot)
            int kbs = kb ^ (r & 7);         // swizzled global source block
            async_load16(A + (size_t)(row0 + r) * K + k0 + kbs * 8, As + g * 8);
            async_load16(BT + (size_t)(col0 + r) * K + k0 + kbs * 8, Bs + g * 8);
        }
        __syncthreads();
#pragma unroll
        for (int kk = 0; kk < 64; kk += 32) {
            s16x8 af[4], bf[4];
            int kxa = ((kk >> 3) + qd) ^ lx;   // un-swizzled block index
#pragma unroll
            for (int i = 0; i < 4; i++)
                af[i] = *(const s16x8*)(As + (wr + i * 16 + ln) * 64 + kxa * 8);
#pragma unroll
            for (int j = 0; j < 4; j++)
                bf[j] = *(const s16x8*)(Bs + (wc + j * 16 + ln) * 64 + kxa * 8);
#pragma unroll
            for (int i = 0; i < 4; i++)
#pragma unroll
                for (int j = 0; j < 4; j++)
                    acc[i][j] = __builtin_amdgcn_mfma_f32_16x16x32_bf16(
                        af[i], bf[j], acc[i][j], 0, 0, 0);
        }
        __syncthreads();
    }

#pragma unroll
    for (int i = 0; i < 4; i++)
#pragma unroll
        for (int j = 0; j < 4; j++) {
            int n = col0 + wc + j * 16 + ln;
#pragma unroll
            for (int r = 0; r < 4; r++) {
                int m = row0 + wr + i * 16 + qd * 4 + r;
                float v = acc[i][j][r];
                if (mode == 0) {
                    int region = n >> 10;
                    if (region == 0) v *= 0.125f;                       // Q / sqrt(dh)
                    else if (region == 3) {                             // G = swish
                        v += bias[n & 1023];
                        v = v / (1.0f + __expf(-v));
                    }
                    Yout[(size_t)m * N + n] = f2b(v);
                } else {
                    Fout[(size_t)m * N + n] = v + bias[n];
                }
            }
        }
}

// ------------------------------------- per-chunk decayed KV state (MFMA)
// A_c[e][d] = sum_j K[j][e] * g^(127-j) * V[j][d];  M=64(e), N=64(d), K=128(j)
#define SJ 136
__global__ __launch_bounds__(256) void chunk_states_kernel(const ushort_t* __restrict__ Y,
                                                           float* __restrict__ Astate) {
    __shared__ ushort_t Ktd[64 * SJ];   // [e][j]  decayed K^T
    __shared__ ushort_t Vtd[64 * SJ];   // [d][j]  V^T
    int c = blockIdx.x, h = blockIdx.y, b = blockIdx.z;
    int t = threadIdx.x;
    float gamma = 1.0f - exp2f(-5.0f - (float)h);
    float l2g = log2f(gamma);
    int row0 = b * SEQ + c * CHUNK;
    int colK = D_MODEL + h * HDIM;

    for (int g = t; g < 1024; g += 256) {
        int j = g >> 3, dg = (g & 7) * 8;
        size_t src = (size_t)(row0 + j) * 4096 + colK + dg;
        u16x8 k8 = *(const u16x8*)(Y + src);
        u16x8 v8 = *(const u16x8*)(Y + src + D_MODEL);
        float dec = exp2f((float)(127 - j) * l2g);
#pragma unroll
        for (int q = 0; q < 8; q++) {
            Ktd[(dg + q) * SJ + j] = f2b(b2f(k8[q]) * dec);
            Vtd[(dg + q) * SJ + j] = v8[q];
        }
    }
    __syncthreads();

    int w = t >> 6, lane = t & 63;
    int wr = w * 16;                 // this wave's 16 e-rows
    int qd = lane >> 4, ln = lane & 15;

    s16x8 af[4];
#pragma unroll
    for (int ks = 0; ks < 4; ks++)
        af[ks] = *(const s16x8*)(Ktd + (wr + ln) * SJ + ks * 32 + qd * 8);

    f32x4 acc[4];
#pragma unroll
    for (int nt = 0; nt < 4; nt++) {
        acc[nt] = (f32x4)0.0f;
#pragma unroll
        for (int ks = 0; ks < 4; ks++) {
            s16x8 bf = *(const s16x8*)(Vtd + (nt * 16 + ln) * SJ + ks * 32 + qd * 8);
            acc[nt] = __builtin_amdgcn_mfma_f32_16x16x32_bf16(af[ks], bf, acc[nt], 0, 0, 0);
        }
    }

    size_t base = ((size_t)((b * NHEADS + h) * NCHUNK + c)) * 4096;
#pragma unroll
    for (int nt = 0; nt < 4; nt++)
#pragma unroll
        for (int r = 0; r < 4; r++)
            Astate[base + (size_t)(wr + qd * 4 + r) * 64 + nt * 16 + ln] = acc[nt][r];
}

// --------------------------------------------- exclusive decay scan over chunk states
__global__ __launch_bounds__(256) void scan_kernel(const float* __restrict__ Astate,
                                                   float* __restrict__ Sprev) {
    int h = blockIdx.x, b = blockIdx.y;
    int bh = b * NHEADS + h;
    float gamma = 1.0f - exp2f(-5.0f - (float)h);
    float gC = exp2f(128.0f * log2f(gamma));
    for (int g = threadIdx.x; g < 1024; g += 256) {
        f32x4 S = (f32x4)0.0f;
        for (int c = 0; c < NCHUNK; c++) {
            size_t off = ((size_t)bh * NCHUNK + c) * 4096 + g * 4;
            *(f32x4*)(Sprev + off) = S;
            f32x4 Ain = *(const f32x4*)(Astate + off);
            S = S * gC + Ain;
        }
    }
}

// --------------------------------------------- per-chunk retention output (MFMA)
// out[i][d] = g^(i+1)*(Q_i . Sprev[:,d]) + sum_{j<=i} g^(i-j) (Q_i.K_j) V_j[d]
#define LDW 72
#define VT_LDW 136
#define CO_ELEMS (128*LDW*2 + 64*LDW*2 + 64*VT_LDW)   // 36352 elems = 72704 B
__global__ __launch_bounds__(256, 2) void chunk_out_kernel(const ushort_t* __restrict__ Y,
                                                           const float* __restrict__ Sprev,
                                                           float* __restrict__ ret) {
    extern __shared__ char smem[];
    ushort_t* Qs   = (ushort_t*)smem;            // [128][72]
    ushort_t* Kc   = Qs + 128 * LDW;             // [128][72]
    ushort_t* Sphi = Kc + 128 * LDW;             // [64][72]
    ushort_t* Splo = Sphi + 64 * LDW;            // [64][72]
    ushort_t* Vt   = Splo + 64 * LDW;            // [64][136]  V^T[d][j]
    ushort_t* Pl   = Qs;                         // [128][136] overlays Qs+Kc

    int c = blockIdx.x, h = blockIdx.y, b = blockIdx.z;
    int t = threadIdx.x;
    float gamma = 1.0f - exp2f(-5.0f - (float)h);
    float l2g = log2f(gamma);
    int row0 = b * SEQ + c * CHUNK;

    for (int g = t; g < 1024; g += 256) {
        int i = g >> 3, dg = (g & 7) * 8;
        size_t src = (size_t)(row0 + i) * 4096 + h * HDIM + dg;
        *(u16x8*)(Qs + i * LDW + dg) = *(const u16x8*)(Y + src);
        *(u16x8*)(Kc + i * LDW + dg) = *(const u16x8*)(Y + src + D_MODEL);
        u16x8 v = *(const u16x8*)(Y + src + 2 * D_MODEL);
#pragma unroll
        for (int k2 = 0; k2 < 8; k2++) Vt[(dg + k2) * VT_LDW + i] = v[k2];
    }
    {
        size_t sbase = ((size_t)((b * NHEADS + h) * NCHUNK + c)) * 4096;
        for (int g = t; g < 1024; g += 256) {
            int e = g >> 4, dg = (g & 15) * 4;
            f32x4 s4 = *(const f32x4*)(Sprev + sbase + e * 64 + dg);
#pragma unroll
            for (int k2 = 0; k2 < 4; k2++) {
                float s = s4[k2];
                ushort_t hb = f2b(s);
                float lo = s - b2f(hb);
                Sphi[(dg + k2) * LDW + e] = hb;
                Splo[(dg + k2) * LDW + e] = f2b(lo);
            }
        }
    }
    __syncthreads();

    int w = t >> 6, lane = t & 63;
    int wr = w * 32;
    int qd = lane >> 4, ln = lane & 15;

    s16x8 aq[2][2];
#pragma unroll
    for (int mt = 0; mt < 2; mt++)
#pragma unroll
        for (int ks = 0; ks < 2; ks++)
            aq[mt][ks] = *(const s16x8*)(Qs + (wr + mt * 16 + ln) * LDW + ks * 32 + qd * 8);

    float prow[2][4], pcolm[8];
#pragma unroll
    for (int mt = 0; mt < 2; mt++)
#pragma unroll
        for (int r = 0; r < 4; r++)
            prow[mt][r] = exp2f((float)(wr + mt * 16 + qd * 4 + r + 1) * l2g);
#pragma unroll
    for (int nt = 0; nt < 8; nt++)
        pcolm[nt] = exp2f(-(float)(nt * 16 + ln + 1) * l2g);

    // phase 1: out = Q @ Sprev (hi + lo), scaled g^(i+1)
    f32x4 out[2][4];
#pragma unroll
    for (int mt = 0; mt < 2; mt++)
#pragma unroll
        for (int dt = 0; dt < 4; dt++) out[mt][dt] = (f32x4)0.0f;
#pragma unroll
    for (int dt = 0; dt < 4; dt++)
#pragma unroll
        for (int ks = 0; ks < 2; ks++) {
            s16x8 bh_ = *(const s16x8*)(Sphi + (dt * 16 + ln) * LDW + ks * 32 + qd * 8);
            s16x8 bl_ = *(const s16x8*)(Splo + (dt * 16 + ln) * LDW + ks * 32 + qd * 8);
#pragma unroll
            for (int mt = 0; mt < 2; mt++) {
                out[mt][dt] = __builtin_amdgcn_mfma_f32_16x16x32_bf16(
                    aq[mt][ks], bh_, out[mt][dt], 0, 0, 0);
                out[mt][dt] = __builtin_amdgcn_mfma_f32_16x16x32_bf16(
                    aq[mt][ks], bl_, out[mt][dt], 0, 0, 0);
            }
        }
#pragma unroll
    for (int mt = 0; mt < 2; mt++)
#pragma unroll
        for (int dt = 0; dt < 4; dt++)
#pragma unroll
            for (int r = 0; r < 4; r++) out[mt][dt][r] *= prow[mt][r];

    // phase 2: scores = Q @ K^T
    f32x4 sc[2][8];
#pragma unroll
    for (int mt = 0; mt < 2; mt++)
#pragma unroll
        for (int nt = 0; nt < 8; nt++) sc[mt][nt] = (f32x4)0.0f;
#pragma unroll
    for (int nt = 0; nt < 8; nt++)
#pragma unroll
        for (int ks = 0; ks < 2; ks++) {
            s16x8 bk = *(const s16x8*)(Kc + (nt * 16 + ln) * LDW + ks * 32 + qd * 8);
#pragma unroll
            for (int mt = 0; mt < 2; mt++)
                sc[mt][nt] = __builtin_amdgcn_mfma_f32_16x16x32_bf16(
                    aq[mt][ks], bk, sc[mt][nt], 0, 0, 0);
        }
    __syncthreads();

    // decay-mask, write P bf16 to LDS (A-operand layout)
#pragma unroll
    for (int mt = 0; mt < 2; mt++)
#pragma unroll
        for (int nt = 0; nt < 8; nt++) {
            int j = nt * 16 + ln;
#pragma unroll
            for (int r = 0; r < 4; r++) {
                int i = wr + mt * 16 + qd * 4 + r;
                float v = (j <= i) ? sc[mt][nt][r] * (prow[mt][r] * pcolm[nt]) : 0.0f;
                Pl[i * VT_LDW + j] = f2b(v);
            }
        }
    __syncthreads();

    // phase 3: out += P @ V
#pragma unroll
    for (int ks = 0; ks < 4; ks++) {
        s16x8 ap[2];
#pragma unroll
        for (int mt = 0; mt < 2; mt++)
            ap[mt] = *(const s16x8*)(Pl + (wr + mt * 16 + ln) * VT_LDW + ks * 32 + qd * 8);
#pragma unroll
        for (int dt = 0; dt < 4; dt++) {
            s16x8 bv = *(const s16x8*)(Vt + (dt * 16 + ln) * VT_LDW + ks * 32 + qd * 8);
#pragma unroll
            for (int mt = 0; mt < 2; mt++)
                out[mt][dt] = __builtin_amdgcn_mfma_f32_16x16x32_bf16(
                    ap[mt], bv, out[mt][dt], 0, 0, 0);
        }
    }

#pragma unroll
    for (int mt = 0; mt < 2; mt++)
#pragma unroll
        for (int dt = 0; dt < 4; dt++)
#pragma unroll
            for (int r = 0; r < 4; r++) {
                int i = wr + mt * 16 + qd * 4 + r;
                ret[(size_t)(row0 + i) * D_MODEL + h * HDIM + dt * 16 + ln] = out[mt][dt][r];
            }
}

// ---------------------------------------------------------------- LayerNorm * gate
__global__ __launch_bounds__(256) void ln_gate_kernel(const float* __restrict__ ret,
                                                      const ushort_t* __restrict__ Y,
                                                      const float* __restrict__ lgam,
                                                      const float* __restrict__ lbet,
                                                      ushort_t* __restrict__ LNG) {
    int row = blockIdx.x, t = threadIdx.x;
    f32x4 v = *(const f32x4*)(ret + (size_t)row * D_MODEL + t * 4);
    float s  = v.x + v.y + v.z + v.w;
    float sq = v.x * v.x + v.y * v.y + v.z * v.z + v.w * v.w;
#pragma unroll
    for (int m = 1; m < 64; m <<= 1) {
        s  += __shfl_xor(s, m);
        sq += __shfl_xor(sq, m);
    }
    __shared__ float red[8];
    int w = t >> 6, lane = t & 63;
    if (lane == 0) { red[w * 2] = s; red[w * 2 + 1] = sq; }
    __syncthreads();
    s  = red[0] + red[2] + red[4] + red[6];
    sq = red[1] + red[3] + red[5] + red[7];
    float mu  = s * (1.0f / 1024.0f);
    float var = sq * (1.0f / 1024.0f) - mu * mu;
    float inv = rsqrtf(var + LN_EPS);
    int col = t * 4;
    u16x4 ug = *(const u16x4*)(Y + (size_t)row * 4096 + 3 * D_MODEL + col);
    u16x4 o;
    o.x = f2b(((v.x - mu) * inv * lgam[col + 0] + lbet[col + 0]) * b2f(ug.x));
    o.y = f2b(((v.y - mu) * inv * lgam[col + 1] + lbet[col + 1]) * b2f(ug.y));
    o.z = f2b(((v.z - mu) * inv * lgam[col + 2] + lbet[col + 2]) * b2f(ug.z));
    o.w = f2b(((v.w - mu) * inv * lgam[col + 3] + lbet[col + 3]) * b2f(ug.w));
    *(u16x4*)(LNG + (size_t)row * D_MODEL + col) = o;
}

// ----------------------------------------------------------------------------
extern "C" void kernel_launch(void* const* d_in, const int* in_sizes, int n_in,
                              void* d_out, int out_size, void* d_ws, size_t ws_size,
                              hipStream_t stream) {
    const float* x   = (const float*)d_in[0];
    const float* Wq  = (const float*)d_in[1];
    const float* Wk  = (const float*)d_in[2];
    const float* Wv  = (const float*)d_in[3];
    const float* Wg  = (const float*)d_in[4];
    const float* bg  = (const float*)d_in[5];
    const float* Wo  = (const float*)d_in[6];
    const float* bo  = (const float*)d_in[7];
    const float* lng = (const float*)d_in[8];
    const float* lnb = (const float*)d_in[9];
    float* out = (float*)d_out;

    char* ws = (char*)d_ws;
    ushort_t* xb    = (ushort_t*)(ws);                       //  8 MB  x bf16
    ushort_t* WcatT = (ushort_t*)(ws + (8ull  << 20));       //  8 MB  [Wq|Wk|Wv|Wg]^T bf16
    ushort_t* WoT   = (ushort_t*)(ws + (16ull << 20));       //  2 MB  Wo^T bf16
    ushort_t* Yb    = (ushort_t*)(ws + (18ull << 20));       // 32 MB  [Q/8|K|V|G] bf16
    float*    retb  = (float*)   (ws + (50ull << 20));       // 16 MB  retention out fp32
    float*    Ast   = (float*)   (ws + (66ull << 20));       //  8 MB  chunk states
    float*    Sprv  = (float*)   (ws + (74ull << 20));       //  8 MB  exclusive-scan states
    ushort_t* LNGb  = (ushort_t*)(ws + (82ull << 20));       //  8 MB  (ln*G) bf16

    const int GEMM_LDS = 2 * 128 * 64 * 2;   // 32768 B
    const int CO_BYTES = CO_ELEMS * 2;       // 72704 B

    hipFuncSetAttribute(reinterpret_cast<const void*>(gemm_kernel),
                        hipFuncAttributeMaxDynamicSharedMemorySize, GEMM_LDS);
    hipFuncSetAttribute(reinterpret_cast<const void*>(chunk_out_kernel),
                        hipFuncAttributeMaxDynamicSharedMemorySize, CO_BYTES);

    cast_x_kernel<<<ROWS * D_MODEL / 1024, 256, 0, stream>>>(x, xb);
    wt_transpose_kernel<<<dim3(32, 32, 5), dim3(32, 8), 0, stream>>>(
        Wq, Wk, Wv, Wg, Wo, WcatT, WoT);

    gemm_kernel<<<dim3(32, 32), 256, GEMM_LDS, stream>>>(
        xb, WcatT, 1024, 4096, 0, bg, Yb, (float*)nullptr);

    chunk_states_kernel<<<dim3(NCHUNK, NHEADS, BATCH), 256, 0, stream>>>(Yb, Ast);
    scan_kernel<<<dim3(NHEADS, BATCH), 256, 0, stream>>>(Ast, Sprv);
    chunk_out_kernel<<<dim3(NCHUNK, NHEADS, BATCH), 256, CO_BYTES, stream>>>(
        Yb, Sprv, retb);

    ln_gate_kernel<<<ROWS, 256, 0, stream>>>(retb, Yb, lng, lnb, LNGb);

    gemm_kernel<<<dim3(8, 32), 256, GEMM_LDS, stream>>>(
        LNGb, WoT, 1024, 1024, 1, bo, (ushort_t*)nullptr, out);
}

// Round 4
// 203.657 us; speedup vs baseline: 1.3930x; 1.0059x over previous
//
#include <hip/hip_runtime.h>

#define D_MODEL 1024
#define NHEADS  16
#define HDIM    64
#define BATCH   2
#define SEQ     2048
#define ROWS    (BATCH*SEQ)      // 4096
#define CHUNK   128
#define NCHUNK  (SEQ/CHUNK)      // 16
#define LN_EPS  1e-3f

typedef unsigned short ushort_t;
typedef __attribute__((ext_vector_type(4))) float          f32x4;
typedef __attribute__((ext_vector_type(8))) short          s16x8;
typedef __attribute__((ext_vector_type(4))) unsigned short u16x4;
typedef __attribute__((ext_vector_type(8))) unsigned short u16x8;

__device__ __forceinline__ ushort_t f2b(float f) {
    union { float f; unsigned int u; } v; v.f = f;
    unsigned int r = v.u + 0x7fffu + ((v.u >> 16) & 1u);
    return (ushort_t)(r >> 16);
}
__device__ __forceinline__ float b2f(ushort_t b) {
    union { unsigned int u; float f; } v; v.u = ((unsigned int)b) << 16;
    return v.f;
}

// async 16B global -> LDS (wave-uniform base + lane*16; m97 pattern)
__device__ __forceinline__ void async_load16(const ushort_t* g, ushort_t* l) {
    __builtin_amdgcn_global_load_lds(
        (const __attribute__((address_space(1))) unsigned int*)(g),
        (__attribute__((address_space(3))) unsigned int*)(l),
        16, 0, 0);
}

// ---------------------------------------------- prep: cast x->bf16 + W transposes
__global__ __launch_bounds__(256) void prep_kernel(
        const float* __restrict__ x,
        const float* __restrict__ Wq, const float* __restrict__ Wk,
        const float* __restrict__ Wv, const float* __restrict__ Wg,
        const float* __restrict__ Wo,
        ushort_t* __restrict__ xb, ushort_t* __restrict__ WcatT,
        ushort_t* __restrict__ WoT) {
    __shared__ float tile[32][33];
    int bid = blockIdx.x, t = threadIdx.x;
    if (bid < 4096) {                       // cast x
        int idx = (bid * 256 + t) * 4;
        f32x4 v = *(const f32x4*)(x + idx);
        u16x4 o;
        o.x = f2b(v.x); o.y = f2b(v.y); o.z = f2b(v.z); o.w = f2b(v.w);
        *(u16x4*)(xb + idx) = o;
        return;
    }
    int zb = bid - 4096;
    int z = zb >> 10;                        // which matrix
    int rem = zb & 1023;
    int bx = rem & 31, by = rem >> 5;
    const float* W = (z == 0) ? Wq : (z == 1) ? Wk : (z == 2) ? Wv : (z == 3) ? Wg : Wo;
    ushort_t* dst = (z < 4) ? (WcatT + (size_t)z * 1024 * 1024) : WoT;
    int n0 = bx * 32, k0 = by * 32;
    int tx = t & 31, ty = t >> 5;
#pragma unroll
    for (int i = 0; i < 4; i++) {
        int k = k0 + ty + i * 8;
        tile[ty + i * 8][tx] = W[(size_t)k * 1024 + n0 + tx];
    }
    __syncthreads();
#pragma unroll
    for (int i = 0; i < 4; i++) {
        int n = n0 + ty + i * 8;
        dst[(size_t)n * 1024 + k0 + tx] = f2b(tile[tx][ty + i * 8]);
    }
}

// ---------------------------------------------------------------- bf16 MFMA GEMM
// C[M x N] = A[M x K] @ B[K x N], B pre-transposed (BT[n][k]).
// global_load_lds width=16 staging, XOR-swizzled 16B blocks (swizzle on the
// GLOBAL source so LDS dest stays lane-contiguous; fragment reads un-swizzle).
// mode 0: N=4096 fused QKVG epilogue -> Y bf16 (Q scaled 1/8, G = swish(.+bg))
// mode 1: N=1024, out fp32 = C + bo
__global__ __launch_bounds__(256, 2) void gemm_kernel(
        const ushort_t* __restrict__ A, const ushort_t* __restrict__ BT,
        int K, int N, int mode, const float* __restrict__ bias,
        ushort_t* __restrict__ Yout, float* __restrict__ Fout) {
    extern __shared__ char smem[];
    ushort_t* As = (ushort_t*)smem;          // [128][64] swizzled
    ushort_t* Bs = As + 128 * 64;            // [128][64] swizzled
    int t = threadIdx.x;
    int row0 = blockIdx.y * 128, col0 = blockIdx.x * 128;
    int w = t >> 6, lane = t & 63;
    int wr = (w >> 1) * 64, wc = (w & 1) * 64;
    int qd = lane >> 4, ln = lane & 15;
    int lx = ln & 7;

    f32x4 acc[4][4];
#pragma unroll
    for (int i = 0; i < 4; i++)
#pragma unroll
        for (int j = 0; j < 4; j++) acc[i][j] = (f32x4)0.0f;

    for (int k0 = 0; k0 < K; k0 += 64) {
#pragma unroll
        for (int p = 0; p < 4; p++) {
            int g = p * 256 + t;
            int r = g >> 3;
            int kb = g & 7;
            int kbs = kb ^ (r & 7);
            async_load16(A + (size_t)(row0 + r) * K + k0 + kbs * 8, As + g * 8);
            async_load16(BT + (size_t)(col0 + r) * K + k0 + kbs * 8, Bs + g * 8);
        }
        __syncthreads();
#pragma unroll
        for (int kk = 0; kk < 64; kk += 32) {
            s16x8 af[4], bf[4];
            int kxa = ((kk >> 3) + qd) ^ lx;
#pragma unroll
            for (int i = 0; i < 4; i++)
                af[i] = *(const s16x8*)(As + (wr + i * 16 + ln) * 64 + kxa * 8);
#pragma unroll
            for (int j = 0; j < 4; j++)
                bf[j] = *(const s16x8*)(Bs + (wc + j * 16 + ln) * 64 + kxa * 8);
#pragma unroll
            for (int i = 0; i < 4; i++)
#pragma unroll
                for (int j = 0; j < 4; j++)
                    acc[i][j] = __builtin_amdgcn_mfma_f32_16x16x32_bf16(
                        af[i], bf[j], acc[i][j], 0, 0, 0);
        }
        __syncthreads();
    }

#pragma unroll
    for (int i = 0; i < 4; i++)
#pragma unroll
        for (int j = 0; j < 4; j++) {
            int n = col0 + wc + j * 16 + ln;
#pragma unroll
            for (int r = 0; r < 4; r++) {
                int m = row0 + wr + i * 16 + qd * 4 + r;
                float v = acc[i][j][r];
                if (mode == 0) {
                    int region = n >> 10;
                    if (region == 0) v *= 0.125f;                       // Q / sqrt(dh)
                    else if (region == 3) {                             // G = swish
                        v += bias[n & 1023];
                        v = v / (1.0f + __expf(-v));
                    }
                    Yout[(size_t)m * N + n] = f2b(v);
                } else {
                    Fout[(size_t)m * N + n] = v + bias[n];
                }
            }
        }
}

// ------------------------------------- per-chunk decayed KV state (MFMA), TRANSPOSED
// AstT[d][e] = sum_j V[j][d] * K[j][e] * g^(127-j);  M=64(d), N=64(e), K=128(j)
#define SJ 136
__global__ __launch_bounds__(256) void chunk_states_kernel(const ushort_t* __restrict__ Y,
                                                           float* __restrict__ Astate) {
    __shared__ ushort_t Ktd[64 * SJ];   // [e][j]  decayed K^T
    __shared__ ushort_t Vtd[64 * SJ];   // [d][j]  V^T
    int c = blockIdx.x, h = blockIdx.y, b = blockIdx.z;
    int t = threadIdx.x;
    float gamma = 1.0f - exp2f(-5.0f - (float)h);
    float l2g = log2f(gamma);
    int row0 = b * SEQ + c * CHUNK;
    int colK = D_MODEL + h * HDIM;

    // staging: thread = (dgi = t&7 d-block, jg = t>>3 row-group of 4)
    {
        int dgi = t & 7, jg = t >> 3;
        u16x8 k8[4], v8[4];
        float dec[4];
#pragma unroll
        for (int r = 0; r < 4; r++) {
            int j = jg * 4 + r;
            size_t src = (size_t)(row0 + j) * 4096 + colK + dgi * 8;
            k8[r] = *(const u16x8*)(Y + src);
            v8[r] = *(const u16x8*)(Y + src + D_MODEL);
            dec[r] = exp2f((float)(127 - j) * l2g);
        }
#pragma unroll
        for (int q = 0; q < 8; q++) {
            int qq = q ^ dgi;                   // bank-decorrelating permutation
            u16x4 pk, pv;
#pragma unroll
            for (int r = 0; r < 4; r++) {
                pk[r] = f2b(b2f(k8[r][qq]) * dec[r]);
                pv[r] = v8[r][qq];
            }
            *(u16x4*)(Ktd + (dgi * 8 + qq) * SJ + jg * 4) = pk;
            *(u16x4*)(Vtd + (dgi * 8 + qq) * SJ + jg * 4) = pv;
        }
    }
    __syncthreads();

    int w = t >> 6, lane = t & 63;
    int wr = w * 16;                 // this wave's 16 d-rows
    int qd = lane >> 4, ln = lane & 15;

    s16x8 af[4];
#pragma unroll
    for (int ks = 0; ks < 4; ks++)
        af[ks] = *(const s16x8*)(Vtd + (wr + ln) * SJ + ks * 32 + qd * 8);

    f32x4 acc[4];
#pragma unroll
    for (int nt = 0; nt < 4; nt++) {
        acc[nt] = (f32x4)0.0f;
#pragma unroll
        for (int ks = 0; ks < 4; ks++) {
            s16x8 bf = *(const s16x8*)(Ktd + (nt * 16 + ln) * SJ + ks * 32 + qd * 8);
            acc[nt] = __builtin_amdgcn_mfma_f32_16x16x32_bf16(af[ks], bf, acc[nt], 0, 0, 0);
        }
    }

    size_t base = ((size_t)((b * NHEADS + h) * NCHUNK + c)) * 4096;
#pragma unroll
    for (int nt = 0; nt < 4; nt++)
#pragma unroll
        for (int r = 0; r < 4; r++)
            Astate[base + (size_t)(wr + qd * 4 + r) * 64 + nt * 16 + ln] = acc[nt][r];
}

// --------------------------------------------- exclusive decay scan (elementwise)
__global__ __launch_bounds__(128) void scan_kernel(const float* __restrict__ Astate,
                                                   float* __restrict__ Sprev) {
    int h = blockIdx.x, b = blockIdx.y;
    int bh = b * NHEADS + h;
    float gamma = 1.0f - exp2f(-5.0f - (float)h);
    float gC = exp2f(128.0f * log2f(gamma));
    int g = blockIdx.z * 128 + threadIdx.x;       // 0..1023 f32x4 group
    size_t base = (size_t)bh * NCHUNK * 4096 + g * 4;
    f32x4 S = (f32x4)0.0f;
    for (int c = 0; c < NCHUNK; c++) {
        *(f32x4*)(Sprev + base + (size_t)c * 4096) = S;
        f32x4 Ain = *(const f32x4*)(Astate + base + (size_t)c * 4096);
        S = S * gC + Ain;
    }
}

// --------------------------------------------- per-chunk retention output (MFMA)
// out[i][d] = g^(i+1)*(Q_i . S[:,d]) + sum_{j<=i} g^(i-j) (Q_i.K_j) V_j[d]
// SprevT global layout is [d][e].
#define LDW 72
#define VT_LDW 136
#define CO_ELEMS (128*LDW*2 + 64*LDW*2 + 64*VT_LDW)   // 36352 elems = 72704 B
__global__ __launch_bounds__(256, 2) void chunk_out_kernel(const ushort_t* __restrict__ Y,
                                                           const float* __restrict__ Sprev,
                                                           float* __restrict__ ret) {
    extern __shared__ char smem[];
    ushort_t* Qs   = (ushort_t*)smem;            // [128][72]
    ushort_t* Kc   = Qs + 128 * LDW;             // [128][72]
    ushort_t* Sphi = Kc + 128 * LDW;             // [64][72]   S^T hi [d][e]
    ushort_t* Splo = Sphi + 64 * LDW;            // [64][72]   S^T lo
    ushort_t* Vt   = Splo + 64 * LDW;            // [64][136]  V^T[d][j]
    ushort_t* Pl   = Qs;                         // [128][136] overlays Qs+Kc

    int c = blockIdx.x, h = blockIdx.y, b = blockIdx.z;
    int t = threadIdx.x;
    float gamma = 1.0f - exp2f(-5.0f - (float)h);
    float l2g = log2f(gamma);
    int row0 = b * SEQ + c * CHUNK;

    // Q,K row-major (vector)
    for (int g = t; g < 1024; g += 256) {
        int i = g >> 3, dg = (g & 7) * 8;
        size_t src = (size_t)(row0 + i) * 4096 + h * HDIM + dg;
        *(u16x8*)(Qs + i * LDW + dg) = *(const u16x8*)(Y + src);
        *(u16x8*)(Kc + i * LDW + dg) = *(const u16x8*)(Y + src + D_MODEL);
    }
    // V transposed: thread = (dgi d-block, jg row-group of 4), u16x4 packed writes
    {
        int dgi = t & 7, jg = t >> 3;
        u16x8 v8[4];
#pragma unroll
        for (int r = 0; r < 4; r++)
            v8[r] = *(const u16x8*)(Y + (size_t)(row0 + jg * 4 + r) * 4096
                                      + 2 * D_MODEL + h * HDIM + dgi * 8);
#pragma unroll
        for (int q = 0; q < 8; q++) {
            int qq = q ^ dgi;
            u16x4 pv;
#pragma unroll
            for (int r = 0; r < 4; r++) pv[r] = v8[r][qq];
            *(u16x4*)(Vt + (dgi * 8 + qq) * VT_LDW + jg * 4) = pv;
        }
    }
    // S^T staging (global already [d][e]): vector read, u16x4 hi/lo writes
    {
        size_t sbase = ((size_t)((b * NHEADS + h) * NCHUNK + c)) * 4096;
        for (int g = t; g < 1024; g += 256) {
            int d = g >> 4, e0 = (g & 15) * 4;
            f32x4 s4 = *(const f32x4*)(Sprev + sbase + d * 64 + e0);
            u16x4 hi4, lo4;
#pragma unroll
            for (int k2 = 0; k2 < 4; k2++) {
                ushort_t hb = f2b(s4[k2]);
                hi4[k2] = hb;
                lo4[k2] = f2b(s4[k2] - b2f(hb));
            }
            *(u16x4*)(Sphi + d * LDW + e0) = hi4;
            *(u16x4*)(Splo + d * LDW + e0) = lo4;
        }
    }
    __syncthreads();

    int w = t >> 6, lane = t & 63;
    int wr = w * 32;
    int qd = lane >> 4, ln = lane & 15;

    s16x8 aq[2][2];
#pragma unroll
    for (int mt = 0; mt < 2; mt++)
#pragma unroll
        for (int ks = 0; ks < 2; ks++)
            aq[mt][ks] = *(const s16x8*)(Qs + (wr + mt * 16 + ln) * LDW + ks * 32 + qd * 8);

    float prow[2][4], pcolm[8];
#pragma unroll
    for (int mt = 0; mt < 2; mt++)
#pragma unroll
        for (int r = 0; r < 4; r++)
            prow[mt][r] = exp2f((float)(wr + mt * 16 + qd * 4 + r + 1) * l2g);
#pragma unroll
    for (int nt = 0; nt < 8; nt++)
        pcolm[nt] = exp2f(-(float)(nt * 16 + ln + 1) * l2g);

    // phase 1: out = Q @ S (hi + lo), scaled g^(i+1)
    f32x4 out[2][4];
#pragma unroll
    for (int mt = 0; mt < 2; mt++)
#pragma unroll
        for (int dt = 0; dt < 4; dt++) out[mt][dt] = (f32x4)0.0f;
#pragma unroll
    for (int dt = 0; dt < 4; dt++)
#pragma unroll
        for (int ks = 0; ks < 2; ks++) {
            s16x8 bh_ = *(const s16x8*)(Sphi + (dt * 16 + ln) * LDW + ks * 32 + qd * 8);
            s16x8 bl_ = *(const s16x8*)(Splo + (dt * 16 + ln) * LDW + ks * 32 + qd * 8);
#pragma unroll
            for (int mt = 0; mt < 2; mt++) {
                out[mt][dt] = __builtin_amdgcn_mfma_f32_16x16x32_bf16(
                    aq[mt][ks], bh_, out[mt][dt], 0, 0, 0);
                out[mt][dt] = __builtin_amdgcn_mfma_f32_16x16x32_bf16(
                    aq[mt][ks], bl_, out[mt][dt], 0, 0, 0);
            }
        }
#pragma unroll
    for (int mt = 0; mt < 2; mt++)
#pragma unroll
        for (int dt = 0; dt < 4; dt++)
#pragma unroll
            for (int r = 0; r < 4; r++) out[mt][dt][r] *= prow[mt][r];

    // phase 2: scores = Q @ K^T
    f32x4 sc[2][8];
#pragma unroll
    for (int mt = 0; mt < 2; mt++)
#pragma unroll
        for (int nt = 0; nt < 8; nt++) sc[mt][nt] = (f32x4)0.0f;
#pragma unroll
    for (int nt = 0; nt < 8; nt++)
#pragma unroll
        for (int ks = 0; ks < 2; ks++) {
            s16x8 bk = *(const s16x8*)(Kc + (nt * 16 + ln) * LDW + ks * 32 + qd * 8);
#pragma unroll
            for (int mt = 0; mt < 2; mt++)
                sc[mt][nt] = __builtin_amdgcn_mfma_f32_16x16x32_bf16(
                    aq[mt][ks], bk, sc[mt][nt], 0, 0, 0);
        }
    __syncthreads();

    // decay-mask, write P bf16 to LDS (A-operand layout)
#pragma unroll
    for (int mt = 0; mt < 2; mt++)
#pragma unroll
        for (int nt = 0; nt < 8; nt++) {
            int j = nt * 16 + ln;
#pragma unroll
            for (int r = 0; r < 4; r++) {
                int i = wr + mt * 16 + qd * 4 + r;
                float v = (j <= i) ? sc[mt][nt][r] * (prow[mt][r] * pcolm[nt]) : 0.0f;
                Pl[i * VT_LDW + j] = f2b(v);
            }
        }
    __syncthreads();

    // phase 3: out += P @ V
#pragma unroll
    for (int ks = 0; ks < 4; ks++) {
        s16x8 ap[2];
#pragma unroll
        for (int mt = 0; mt < 2; mt++)
            ap[mt] = *(const s16x8*)(Pl + (wr + mt * 16 + ln) * VT_LDW + ks * 32 + qd * 8);
#pragma unroll
        for (int dt = 0; dt < 4; dt++) {
            s16x8 bv = *(const s16x8*)(Vt + (dt * 16 + ln) * VT_LDW + ks * 32 + qd * 8);
#pragma unroll
            for (int mt = 0; mt < 2; mt++)
                out[mt][dt] = __builtin_amdgcn_mfma_f32_16x16x32_bf16(
                    ap[mt], bv, out[mt][dt], 0, 0, 0);
        }
    }

#pragma unroll
    for (int mt = 0; mt < 2; mt++)
#pragma unroll
        for (int dt = 0; dt < 4; dt++)
#pragma unroll
            for (int r = 0; r < 4; r++) {
                int i = wr + mt * 16 + qd * 4 + r;
                ret[(size_t)(row0 + i) * D_MODEL + h * HDIM + dt * 16 + ln] = out[mt][dt][r];
            }
}

// ---------------------------------------------------------------- LayerNorm * gate
__global__ __launch_bounds__(256) void ln_gate_kernel(const float* __restrict__ ret,
                                                      const ushort_t* __restrict__ Y,
                                                      const float* __restrict__ lgam,
                                                      const float* __restrict__ lbet,
                                                      ushort_t* __restrict__ LNG) {
    int row = blockIdx.x, t = threadIdx.x;
    f32x4 v = *(const f32x4*)(ret + (size_t)row * D_MODEL + t * 4);
    float s  = v.x + v.y + v.z + v.w;
    float sq = v.x * v.x + v.y * v.y + v.z * v.z + v.w * v.w;
#pragma unroll
    for (int m = 1; m < 64; m <<= 1) {
        s  += __shfl_xor(s, m);
        sq += __shfl_xor(sq, m);
    }
    __shared__ float red[8];
    int w = t >> 6, lane = t & 63;
    if (lane == 0) { red[w * 2] = s; red[w * 2 + 1] = sq; }
    __syncthreads();
    s  = red[0] + red[2] + red[4] + red[6];
    sq = red[1] + red[3] + red[5] + red[7];
    float mu  = s * (1.0f / 1024.0f);
    float var = sq * (1.0f / 1024.0f) - mu * mu;
    float inv = rsqrtf(var + LN_EPS);
    int col = t * 4;
    u16x4 ug = *(const u16x4*)(Y + (size_t)row * 4096 + 3 * D_MODEL + col);
    u16x4 o;
    o.x = f2b(((v.x - mu) * inv * lgam[col + 0] + lbet[col + 0]) * b2f(ug.x));
    o.y = f2b(((v.y - mu) * inv * lgam[col + 1] + lbet[col + 1]) * b2f(ug.y));
    o.z = f2b(((v.z - mu) * inv * lgam[col + 2] + lbet[col + 2]) * b2f(ug.z));
    o.w = f2b(((v.w - mu) * inv * lgam[col + 3] + lbet[col + 3]) * b2f(ug.w));
    *(u16x4*)(LNG + (size_t)row * D_MODEL + col) = o;
}

// ----------------------------------------------------------------------------
extern "C" void kernel_launch(void* const* d_in, const int* in_sizes, int n_in,
                              void* d_out, int out_size, void* d_ws, size_t ws_size,
                              hipStream_t stream) {
    const float* x   = (const float*)d_in[0];
    const float* Wq  = (const float*)d_in[1];
    const float* Wk  = (const float*)d_in[2];
    const float* Wv  = (const float*)d_in[3];
    const float* Wg  = (const float*)d_in[4];
    const float* bg  = (const float*)d_in[5];
    const float* Wo  = (const float*)d_in[6];
    const float* bo  = (const float*)d_in[7];
    const float* lng = (const float*)d_in[8];
    const float* lnb = (const float*)d_in[9];
    float* out = (float*)d_out;

    char* ws = (char*)d_ws;
    ushort_t* xb    = (ushort_t*)(ws);                       //  8 MB  x bf16
    ushort_t* WcatT = (ushort_t*)(ws + (8ull  << 20));       //  8 MB  [Wq|Wk|Wv|Wg]^T bf16
    ushort_t* WoT   = (ushort_t*)(ws + (16ull << 20));       //  2 MB  Wo^T bf16
    ushort_t* Yb    = (ushort_t*)(ws + (18ull << 20));       // 32 MB  [Q/8|K|V|G] bf16
    float*    retb  = (float*)   (ws + (50ull << 20));       // 16 MB  retention out fp32
    float*    Ast   = (float*)   (ws + (66ull << 20));       //  8 MB  chunk states [d][e]
    float*    Sprv  = (float*)   (ws + (74ull << 20));       //  8 MB  scanned states [d][e]
    ushort_t* LNGb  = (ushort_t*)(ws + (82ull << 20));       //  8 MB  (ln*G) bf16

    const int GEMM_LDS = 2 * 128 * 64 * 2;   // 32768 B
    const int CO_BYTES = CO_ELEMS * 2;       // 72704 B

    hipFuncSetAttribute(reinterpret_cast<const void*>(gemm_kernel),
                        hipFuncAttributeMaxDynamicSharedMemorySize, GEMM_LDS);
    hipFuncSetAttribute(reinterpret_cast<const void*>(chunk_out_kernel),
                        hipFuncAttributeMaxDynamicSharedMemorySize, CO_BYTES);

    prep_kernel<<<4096 + 5120, 256, 0, stream>>>(x, Wq, Wk, Wv, Wg, Wo, xb, WcatT, WoT);

    gemm_kernel<<<dim3(32, 32), 256, GEMM_LDS, stream>>>(
        xb, WcatT, 1024, 4096, 0, bg, Yb, (float*)nullptr);

    chunk_states_kernel<<<dim3(NCHUNK, NHEADS, BATCH), 256, 0, stream>>>(Yb, Ast);
    scan_kernel<<<dim3(NHEADS, BATCH, 8), 128, 0, stream>>>(Ast, Sprv);
    chunk_out_kernel<<<dim3(NCHUNK, NHEADS, BATCH), 256, CO_BYTES, stream>>>(
        Yb, Sprv, retb);

    ln_gate_kernel<<<ROWS, 256, 0, stream>>>(retb, Yb, lng, lnb, LNGb);

    gemm_kernel<<<dim3(8, 32), 256, GEMM_LDS, stream>>>(
        LNGb, WoT, 1024, 1024, 1, bo, (ushort_t*)nullptr, out);
}